// Round 13
// baseline (658.244 us; speedup 1.0000x reference)
//
#include <hip/hip_runtime.h>
#include <math.h>

// Problem constants
#define BB 16
#define NN 1024
#define DD 512
#define KK 8
#define EPS_ 1e-8f
#define LN_EPS_ 1e-5f
// -0.5 * D * log(2*pi)
#define GLL_C0 (-470.4965290007924f)

typedef __attribute__((ext_vector_type(8))) short short8;
typedef __attribute__((ext_vector_type(4))) short short4v;
typedef __attribute__((ext_vector_type(4))) float f32x4;
typedef __attribute__((ext_vector_type(4))) int int4v;

static __device__ inline short f2bf(float f) {
    unsigned u = __builtin_bit_cast(unsigned, f);
    u = (u + 0x7fff + ((u >> 16) & 1)) >> 16;
    return (short)u;
}
static __device__ inline float bf2f(short s) {
    unsigned u = ((unsigned)(unsigned short)s) << 16;
    return __builtin_bit_cast(float, u);
}

struct Params {
    const float *emb, *noise_init, *noise_final, *slots_mu, *slots_logsg,
                *mixing_co, *Wk, *bk, *Wq, *bq, *Wv, *bv, *ln_g, *ln_b;
    float *out;
    float *queries, *attn, *s1p, *s2p, *off, *mix16, *colsum;
    int *cnt;
    short *Abf, *Kbf, *Vbf, *WtKV, *WqT, *slotbf, *F_bt;
};

// ===========================================================================
// 1) pre: u in [0,4992) : LN+cast | weight transpose | slot init
//    (verified correct rounds 7-12)
// ===========================================================================
__global__ __launch_bounds__(256) void k_pre(Params p)
{
    __shared__ __align__(16) short eb[4352];
    int u = blockIdx.x, tid = threadIdx.x;
    if (u < 4096) {
        int row  = u * 4 + (tid >> 6);
        int lane = tid & 63;
        const float* e = p.emb + (size_t)row * DD + lane * 8;
        float4 v0 = *(const float4*)e;
        float4 v1 = *(const float4*)(e + 4);
        float v[8] = {v0.x, v0.y, v0.z, v0.w, v1.x, v1.y, v1.z, v1.w};
        float s = 0.0f;
#pragma unroll
        for (int j = 0; j < 8; j++) s += v[j];
#pragma unroll
        for (int off = 32; off; off >>= 1) s += __shfl_xor(s, off);
        float m = s * (1.0f / DD);
        float vs = 0.0f;
#pragma unroll
        for (int j = 0; j < 8; j++) { float d = v[j] - m; vs = fmaf(d, d, vs); }
#pragma unroll
        for (int off = 32; off; off >>= 1) vs += __shfl_xor(vs, off);
        float rstd = rsqrtf(vs * (1.0f / DD) + LN_EPS_);

        float4 g0 = *(const float4*)&p.ln_g[lane * 8];
        float4 g1 = *(const float4*)&p.ln_g[lane * 8 + 4];
        float4 b0 = *(const float4*)&p.ln_b[lane * 8];
        float4 b1 = *(const float4*)&p.ln_b[lane * 8 + 4];
        float g[8] = {g0.x, g0.y, g0.z, g0.w, g1.x, g1.y, g1.z, g1.w};
        float bb[8] = {b0.x, b0.y, b0.z, b0.w, b1.x, b1.y, b1.z, b1.w};
        short8 o;
#pragma unroll
        for (int j = 0; j < 8; j++) o[j] = f2bf(fmaf((v[j] - m) * rstd, g[j], bb[j]));
        *(short8*)&p.Abf[(size_t)row * DD + lane * 8] = o;
    } else if (u < 4864) {
        int idx = u - 4096;
        int z = idx >> 8, rem = idx & 255;
        const float* W = (z == 0) ? p.Wk : (z == 1) ? p.Wv : p.Wq;
        short* T; int nbase;
        if (z < 2) { T = p.WtKV; nbase = z * 512; } else { T = p.WqT; nbase = 0; }
        int k0 = (rem & 15) * 32, n0 = (rem >> 4) * 32;
        int tx = tid & 31, ty = tid >> 5;
        float (*t)[33] = (float (*)[33])eb;
#pragma unroll
        for (int q = 0; q < 4; q++)
            t[ty + q * 8][tx] = W[(size_t)(k0 + ty + q * 8) * DD + n0 + tx];
        __syncthreads();
#pragma unroll
        for (int q = 0; q < 4; q++)
            T[(size_t)(nbase + n0 + ty + q * 8) * DD + k0 + tx] = f2bf(t[tx][ty + q * 8]);
    } else {
        int idx = u - 4864;
        int b = idx >> 3, k = idx & 7;
#pragma unroll
        for (int q = 0; q < 2; q++) {
            int d = tid + q * 256;
            float sg = expf(p.slots_logsg[k * DD + d]);
            float sl = fmaf(sg, p.noise_init[((size_t)(b * KK + k)) * DD + d],
                            p.slots_mu[k * DD + d]);
            p.slotbf[((size_t)(b * KK + k)) * DD + d] = f2bf(sl);
        }
    }
}

// ===========================================================================
// 2) gemm: u in [0,1032) : 128x128 MFMA GEMM (round-12, measured best):
//    LDS staging + register-prefetch pipeline + XCD swizzle; single-pass
//    coalesced epilogue (x<4 -> Kbf, x>=4 -> Vbf, u>=1024 -> queries).
// ===========================================================================
__global__ __launch_bounds__(256) void k_gemm(Params p)
{
    __shared__ __align__(16) short smem[16384];   // 32 KB: As | Bs
    int u = blockIdx.x, tid = threadIdx.x;
    int w = tid >> 6, l = tid & 63;
    int x, by, qmode;
    if (u >= 1024) { qmode = 1; x = u - 1024; if (x >= 4) return; by = 128; }
    else           { qmode = 0; x = u >> 7;   by = u & 127; }
    const short* A  = qmode ? p.slotbf : p.Abf + (size_t)by * 128 * DD;
    const short* Bt = qmode ? p.WqT : p.WtKV;
    int row0 = qmode ? 0 : by * 128;
    int col0 = x * 128;

    short* As = smem;
    short* Bs = smem + 8192;
    int sr = l >> 3;
    int sg_off = ((l & 7) ^ sr) * 8;
    int mq = (w & 1) * 64, nq = (w >> 1) * 64;
    int fr = l & 15;
    int orow = (l >> 4) * 4, ocol = l & 15;

    int4v ra[4], rb4[4];
    auto LOADR = [&](int k0) {
#pragma unroll
        for (int j = 0; j < 4; j++) {
            int rbj = w * 32 + j * 8;
            int r   = rbj + sr;
            ra[j]  = *(const int4v*)(A  + (size_t)r * DD + k0 + sg_off);
            rb4[j] = *(const int4v*)(Bt + (size_t)(col0 + r) * DD + k0 + sg_off);
        }
    };
    auto WRITES = [&]() {
#pragma unroll
        for (int j = 0; j < 4; j++) {
            int rbj = w * 32 + j * 8;
            *(int4v*)&As[rbj * 64 + l * 8] = ra[j];
            *(int4v*)&Bs[rbj * 64 + l * 8] = rb4[j];
        }
    };

    f32x4 acc[4][4] = {};
    LOADR(0);
    WRITES();
    __syncthreads();
    for (int i = 0; i < 8; i++) {
        if (i < 7) LOADR((i + 1) * 64);
#pragma unroll
        for (int kk = 0; kk < 2; kk++) {
            int g = kk * 4 + (l >> 4);
            short8 af[4], bfv[4];
#pragma unroll
            for (int mi = 0; mi < 4; mi++)
                af[mi] = *(const short8*)&As[(mq + mi * 16 + fr) * 64 + (g ^ (fr & 7)) * 8];
#pragma unroll
            for (int ni = 0; ni < 4; ni++)
                bfv[ni] = *(const short8*)&Bs[(nq + ni * 16 + fr) * 64 + (g ^ (fr & 7)) * 8];
#pragma unroll
            for (int mi = 0; mi < 4; mi++)
#pragma unroll
                for (int ni = 0; ni < 4; ni++)
                    acc[mi][ni] = __builtin_amdgcn_mfma_f32_16x16x32_bf16(
                        af[mi], bfv[ni], acc[mi][ni], 0, 0, 0);
        }
        __syncthreads();
        if (i < 7) {
            WRITES();
            __syncthreads();
        }
    }

    float bvv[4];
#pragma unroll
    for (int ni = 0; ni < 4; ni++) {
        int col = col0 + nq + ni * 16 + ocol;
        bvv[ni] = qmode ? p.bq[col] : (x < 4 ? p.bk[col] : p.bv[col - 512]);
    }

    if (qmode) {
#pragma unroll
        for (int ni = 0; ni < 4; ni++) {
            int col = col0 + nq + ni * 16 + ocol;
#pragma unroll
            for (int mi = 0; mi < 4; mi++)
#pragma unroll
                for (int r = 0; r < 4; r++)
                    p.queries[(size_t)(mq + mi * 16 + orow + r) * DD + col] =
                        acc[mi][ni][r] + bvv[ni];
        }
    } else {
        short* eb = smem;   // 32 KB epilogue buffer
        short* dst = (x < 4) ? p.Kbf : p.Vbf;
        int ccol0 = (x & 3) * 128;
#pragma unroll
        for (int mi = 0; mi < 4; mi++)
#pragma unroll
            for (int r = 0; r < 4; r++) {
                int row = mq + mi * 16 + orow + r;
                int sw = ((row >> 2) & 3) << 1;
#pragma unroll
                for (int ni = 0; ni < 4; ni++) {
                    int colg = nq + ni * 16 + ocol;
                    eb[row * 128 + (((colg >> 3) ^ sw) * 8) + (colg & 7)] =
                        f2bf(acc[mi][ni][r] + bvv[ni]);
                }
            }
        __syncthreads();
#pragma unroll
        for (int i = 0; i < 8; i++) {
            int row = i * 16 + w * 4 + (l >> 4);
            int c = l & 15;
            int cc = c ^ (((row >> 2) & 3) << 1);
            short8 vv = *(const short8*)&eb[row * 128 + cc * 8];
            *(short8*)&dst[(size_t)(row0 + row) * 512 + ccol0 + c * 8] = vv;
        }
    }
}

// ===========================================================================
// 3) fprep0: u in [0,256) : initial F/off/mix + colsum & counter reset
// ===========================================================================
__global__ __launch_bounds__(256) void k_fprep0(Params p)
{
    __shared__ float red[512];
    int u = blockIdx.x, tid = threadIdx.x;
    int b = u >> 4, k = u & 15;
    if (u < 16 && tid == 0) p.cnt[u] = 0;
    short* Fr = p.F_bt + (size_t)(b * 16 + k) * 1024;
    if (k >= KK) {
        short4v zv = {0, 0, 0, 0};
        *(short4v*)&Fr[tid * 4] = zv;
        if (tid == 0) { p.off[b * 16 + k] = 0.0f; p.mix16[b * 16 + k] = 0.0f; }
        return;
    }
    float* rc = red;
    float* rl = red + 256;
    float c = 0.0f, ld = 0.0f;
#pragma unroll
    for (int q = 0; q < 2; q++) {
        int d = tid * 2 + q;
        float sg = expf(p.slots_logsg[k * DD + d]);
        float iv = 1.0f / (sg * sg + EPS_);
        float qv = p.queries[((size_t)(b * KK + k)) * DD + d];
        Fr[d]       = f2bf(-0.5f * iv);
        Fr[512 + d] = f2bf(qv * iv);
        c  = fmaf(qv * qv, iv, c);
        ld += logf(fabsf(sg) + EPS_);
    }
    rc[tid] = c; rl[tid] = ld;
    __syncthreads();
    for (int s = 128; s > 0; s >>= 1) {
        if (tid < s) { rc[tid] += rc[tid + s]; rl[tid] += rl[tid + s]; }
        __syncthreads();
    }
    if (tid == 0) {
        p.off[b * 16 + k]    = GLL_C0 - 0.5f * rl[0] - 0.5f * rc[0];
        p.mix16[b * 16 + k]  = p.mixing_co[k];
        p.colsum[b * KK + k] = 0.0f;
    }
}

// ===========================================================================
// 4) FUSED gll + musigma + (last-block-per-b) fprep/final.
//    grid (512) = (b, chunk of 32 rows), 512 threads.
//    Phase A: 8 waves = 2 row-tiles x 4 K-splits, keys squared on the fly,
//    LDS reduce, normalize; attn -> LDS (+global if mode==1); colsum atomics.
//    Phase B: s1/s2 partials (1 d-column/thread).
//    Then threadfence + per-b counter: the LAST block of each b does
//      mode 0: F/off/mix update + colsum/counter reset (was k_fprep)
//      mode 1: slots-out + attn^T-out for its b (was k_final)
// ===========================================================================
__global__ __launch_bounds__(512) void k_gllmu(Params p, int mode)
{
    __shared__ f32x4 red[3][2][64];   // 6 KB
    __shared__ float asml[32 * KK];   // 1 KB
    __shared__ float redk[2][8][8];   // 512 B
    __shared__ int lastS;
    int u = blockIdx.x, tid = threadIdx.x;
    int w = tid >> 6, l = tid & 63;
    int b = u >> 5, chunk = u & 31;
    int n0 = chunk * 32;
    int t = w & 1, ks = w >> 1;       // row-tile, K-split (0..3)

    // ---- phase A ----
    const short* Ka = p.Kbf + ((size_t)(b * NN + n0 + t * 16 + (l & 15))) * 512
                      + ks * 128 + (l >> 4) * 8;
    const short* Fi = p.F_bt + (size_t)(b * 16 + (l & 15)) * 1024
                      + ks * 128 + (l >> 4) * 8;
    f32x4 acc0 = {}, acc1 = {};
#pragma unroll
    for (int j = 0; j < 4; j++) {
        short8 kf = *(const short8*)&Ka[j * 32];
        short8 f0 = *(const short8*)&Fi[j * 32];         // -0.5*invvar
        short8 f1 = *(const short8*)&Fi[j * 32 + 512];   // q*invvar
        short8 k2;
#pragma unroll
        for (int e = 0; e < 8; e++) {
            float kv = bf2f(kf[e]);
            k2[e] = f2bf(kv * kv);
        }
        acc0 = __builtin_amdgcn_mfma_f32_16x16x32_bf16(k2, f0, acc0, 0, 0, 0);
        acc1 = __builtin_amdgcn_mfma_f32_16x16x32_bf16(kf, f1, acc1, 0, 0, 0);
    }
    f32x4 acc = acc0 + acc1;

    if (ks) red[ks - 1][t][l] = acc;
    __syncthreads();
    if (ks == 0) {
#pragma unroll
        for (int i = 0; i < 3; i++) acc += red[i][t][l];
        int col = l & 15;
        int rloc = t * 16 + (l >> 4) * 4;
        float offv = p.off[b * 16 + col];
        float mixv = p.mix16[b * 16 + col];
        float a[4], den[4];
#pragma unroll
        for (int r = 0; r < 4; r++) {
            a[r] = mixv * (acc[r] + offv);
            den[r] = a[r];
        }
#pragma unroll
        for (int mask = 1; mask <= 8; mask <<= 1)
#pragma unroll
            for (int r = 0; r < 4; r++) den[r] += __shfl_xor(den[r], mask);
        float csl = 0.0f;
        if (col < KK) {
#pragma unroll
            for (int r = 0; r < 4; r++) {
                float vv = a[r] / den[r];
                asml[(rloc + r) * KK + col] = vv;
                if (mode) p.attn[((size_t)(b * NN + n0 + rloc + r)) * KK + col] = vv;
                csl += vv;
            }
        }
        csl += __shfl_xor(csl, 16);
        csl += __shfl_xor(csl, 32);
        if (l < KK) atomicAdd(&p.colsum[b * KK + l], csl);
    }
    __syncthreads();

    // ---- phase B: 512 threads, one d-column each over 32 rows ----
    {
        float s1[KK] = {}, s2[KK] = {};
        const short* vb = p.Vbf + ((size_t)(b * NN + n0)) * DD + tid;
#pragma unroll 4
        for (int nn = 0; nn < 32; nn++) {
            float v = bf2f(vb[(size_t)nn * DD]);
            float vq = v * v;
            float4 a0 = *(const float4*)&asml[nn * KK];
            float4 a1 = *(const float4*)&asml[nn * KK + 4];
            float aa[8] = {a0.x, a0.y, a0.z, a0.w, a1.x, a1.y, a1.z, a1.w};
#pragma unroll
            for (int k = 0; k < KK; k++) {
                s1[k] = fmaf(aa[k], v, s1[k]);
                s2[k] = fmaf(aa[k], vq, s2[k]);
            }
        }
        size_t base = ((size_t)(b * 32 + chunk) * KK) * DD + tid;
#pragma unroll
        for (int k = 0; k < KK; k++) {
            p.s1p[base + (size_t)k * DD] = s1[k];
            p.s2p[base + (size_t)k * DD] = s2[k];
        }
    }

    // ---- last-block-per-b epilogue ----
    __threadfence();
    __syncthreads();
    if (tid == 0) lastS = (atomicAdd(&p.cnt[b], 1) == 31) ? 1 : 0;
    __syncthreads();
    if (!lastS) return;
    __threadfence();   // acquire: see all 32 blocks' s1p/s2p/colsum/attn
    if (tid == 0) p.cnt[b] = 0;

    int d = tid;       // 512 threads = 512 d columns
    float csv[KK], invv[KK], ssv[KK];
#pragma unroll
    for (int k = 0; k < KK; k++) {
        csv[k]  = p.colsum[b * KK + k];
        invv[k] = 1.0f / (csv[k] + EPS_);
        ssv[k]  = csv[k] * invv[k];
    }

    if (mode == 0) {
        float ck[KK], lk[KK];
#pragma unroll
        for (int k = 0; k < KK; k++) {
            float s1 = 0.0f, s2 = 0.0f;
            for (int ns = 0; ns < 32; ns++) {
                size_t o = ((size_t)(b * 32 + ns) * KK + k) * DD + d;
                s1 += p.s1p[o];
                s2 += p.s2p[o];
            }
            float m  = s1 * invv[k];
            float sg = s2 * invv[k] - m * m * (2.0f - ssv[k]);
            float iv = 1.0f / (sg * sg + EPS_);
            float qv = p.queries[((size_t)(b * KK + k)) * DD + d];
            short* Fr = p.F_bt + (size_t)(b * 16 + k) * 1024;
            Fr[d]       = f2bf(-0.5f * iv);
            Fr[512 + d] = f2bf(qv * iv);
            ck[k] = qv * qv * iv;
            lk[k] = logf(fabsf(sg) + EPS_);
        }
        // reduce ck/lk per k across 512 threads
        int wv = tid >> 6, ln = tid & 63;
#pragma unroll
        for (int k = 0; k < KK; k++) {
            float cv = ck[k], lv = lk[k];
#pragma unroll
            for (int off = 32; off; off >>= 1) {
                cv += __shfl_xor(cv, off);
                lv += __shfl_xor(lv, off);
            }
            if (ln == 0) { redk[0][wv][k] = cv; redk[1][wv][k] = lv; }
        }
        __syncthreads();
        if (tid < KK) {
            float cs_ = 0.0f, ls_ = 0.0f;
#pragma unroll
            for (int wv2 = 0; wv2 < 8; wv2++) {
                cs_ += redk[0][wv2][tid];
                ls_ += redk[1][wv2][tid];
            }
            p.off[b * 16 + tid]    = GLL_C0 - 0.5f * ls_ - 0.5f * cs_;
            p.mix16[b * 16 + tid]  = ssv[tid] * (1.0f / NN);
            p.colsum[b * KK + tid] = 0.0f;
        }
    } else {
        // slots out
#pragma unroll
        for (int k = 0; k < KK; k++) {
            float s1 = 0.0f, s2 = 0.0f;
            for (int ns = 0; ns < 32; ns++) {
                size_t o = ((size_t)(b * 32 + ns) * KK + k) * DD + d;
                s1 += p.s1p[o];
                s2 += p.s2p[o];
            }
            float m  = s1 * invv[k];
            float sg = s2 * invv[k] - m * m * (2.0f - ssv[k]);
            int gid = (b * KK + k) * DD + d;
            p.out[gid] = fmaf(fmaxf(fabsf(sg), EPS_), p.noise_final[gid], m);
        }
        // attn^T out for this b: 8192 elems / 512 threads = 16 each
#pragma unroll
        for (int i = 0; i < 16; i++) {
            int idx = i * 512 + tid;         // k*1024 + n
            int k = idx >> 10, n = idx & 1023;
            p.out[BB * KK * DD + (b * KK + k) * 1024 + n] =
                p.attn[((size_t)(b * NN + n)) * KK + k] / (csv[k] + EPS_);
        }
    }
}

// ===========================================================================
extern "C" void kernel_launch(void* const* d_in, const int* in_sizes, int n_in,
                              void* d_out, int out_size, void* d_ws, size_t ws_size,
                              hipStream_t stream)
{
    Params pp;
    pp.emb         = (const float*)d_in[0];
    pp.noise_init  = (const float*)d_in[1];
    pp.noise_final = (const float*)d_in[2];
    pp.slots_mu    = (const float*)d_in[3];
    pp.slots_logsg = (const float*)d_in[4];
    pp.mixing_co   = (const float*)d_in[5];
    pp.Wk          = (const float*)d_in[6];
    pp.bk          = (const float*)d_in[7];
    pp.Wq          = (const float*)d_in[8];
    pp.bq          = (const float*)d_in[9];
    pp.Wv          = (const float*)d_in[10];
    pp.bv          = (const float*)d_in[11];
    pp.ln_g        = (const float*)d_in[12];
    pp.ln_b        = (const float*)d_in[13];
    pp.out         = (float*)d_out;

    float* ws = (float*)d_ws;
    pp.queries = ws;
    pp.attn    = pp.queries + BB * KK * DD;
    pp.s1p     = pp.attn + BB * NN * KK;
    pp.s2p     = pp.s1p + (size_t)BB * 32 * KK * DD;
    pp.off     = pp.s2p + (size_t)BB * 32 * KK * DD;
    pp.mix16   = pp.off + BB * 16;
    pp.colsum  = pp.mix16 + BB * 16;
    pp.cnt     = (int*)(pp.colsum + BB * KK);
    pp.Abf     = (short*)(pp.cnt + 64);
    pp.Kbf     = pp.Abf + (size_t)BB * NN * DD;
    pp.Vbf     = pp.Kbf + (size_t)BB * NN * DD;
    pp.WtKV    = pp.Vbf + (size_t)BB * NN * DD;
    pp.WqT     = pp.WtKV + (size_t)1024 * DD;
    pp.slotbf  = pp.WqT + (size_t)DD * DD;
    pp.F_bt    = pp.slotbf + (size_t)BB * KK * DD;

    k_pre<<<4992, 256, 0, stream>>>(pp);
    k_gemm<<<1032, 256, 0, stream>>>(pp);
    k_fprep0<<<256, 256, 0, stream>>>(pp);
    for (int it = 0; it < 3; it++)
        k_gllmu<<<512, 512, 0, stream>>>(pp, it == 2 ? 1 : 0);
}

// Round 14
// 618.761 us; speedup vs baseline: 1.0638x; 1.0638x over previous
//
#include <hip/hip_runtime.h>
#include <math.h>

// Problem constants
#define BB 16
#define NN 1024
#define DD 512
#define KK 8
#define EPS_ 1e-8f
#define LN_EPS_ 1e-5f
// -0.5 * D * log(2*pi)
#define GLL_C0 (-470.4965290007924f)

typedef __attribute__((ext_vector_type(8))) short short8;
typedef __attribute__((ext_vector_type(4))) short short4v;
typedef __attribute__((ext_vector_type(4))) float f32x4;
typedef __attribute__((ext_vector_type(4))) int int4v;

static __device__ inline short f2bf(float f) {
    unsigned u = __builtin_bit_cast(unsigned, f);
    u = (u + 0x7fff + ((u >> 16) & 1)) >> 16;
    return (short)u;
}
static __device__ inline float bf2f(short s) {
    unsigned u = ((unsigned)(unsigned short)s) << 16;
    return __builtin_bit_cast(float, u);
}

struct Params {
    const float *emb, *noise_init, *noise_final, *slots_mu, *slots_logsg,
                *mixing_co, *Wk, *bk, *Wq, *bq, *Wv, *bv, *ln_g, *ln_b;
    float *out;
    float *queries, *attn, *s1p, *s2p, *off, *mix16, *colsum;
    int *cnt;
    short *Abf, *Kbf, *Vbf, *WtKV, *WqT, *slotbf, *F_bt;
};

// ===========================================================================
// 1) pre: u in [0,4992) : LN+cast | weight transpose | slot init
//    (verified correct rounds 7-13)
// ===========================================================================
__global__ __launch_bounds__(256) void k_pre(Params p)
{
    __shared__ __align__(16) short eb[4352];
    int u = blockIdx.x, tid = threadIdx.x;
    if (u < 4096) {
        int row  = u * 4 + (tid >> 6);
        int lane = tid & 63;
        const float* e = p.emb + (size_t)row * DD + lane * 8;
        float4 v0 = *(const float4*)e;
        float4 v1 = *(const float4*)(e + 4);
        float v[8] = {v0.x, v0.y, v0.z, v0.w, v1.x, v1.y, v1.z, v1.w};
        float s = 0.0f;
#pragma unroll
        for (int j = 0; j < 8; j++) s += v[j];
#pragma unroll
        for (int off = 32; off; off >>= 1) s += __shfl_xor(s, off);
        float m = s * (1.0f / DD);
        float vs = 0.0f;
#pragma unroll
        for (int j = 0; j < 8; j++) { float d = v[j] - m; vs = fmaf(d, d, vs); }
#pragma unroll
        for (int off = 32; off; off >>= 1) vs += __shfl_xor(vs, off);
        float rstd = rsqrtf(vs * (1.0f / DD) + LN_EPS_);

        float4 g0 = *(const float4*)&p.ln_g[lane * 8];
        float4 g1 = *(const float4*)&p.ln_g[lane * 8 + 4];
        float4 b0 = *(const float4*)&p.ln_b[lane * 8];
        float4 b1 = *(const float4*)&p.ln_b[lane * 8 + 4];
        float g[8] = {g0.x, g0.y, g0.z, g0.w, g1.x, g1.y, g1.z, g1.w};
        float bb[8] = {b0.x, b0.y, b0.z, b0.w, b1.x, b1.y, b1.z, b1.w};
        short8 o;
#pragma unroll
        for (int j = 0; j < 8; j++) o[j] = f2bf(fmaf((v[j] - m) * rstd, g[j], bb[j]));
        *(short8*)&p.Abf[(size_t)row * DD + lane * 8] = o;
    } else if (u < 4864) {
        int idx = u - 4096;
        int z = idx >> 8, rem = idx & 255;
        const float* W = (z == 0) ? p.Wk : (z == 1) ? p.Wv : p.Wq;
        short* T; int nbase;
        if (z < 2) { T = p.WtKV; nbase = z * 512; } else { T = p.WqT; nbase = 0; }
        int k0 = (rem & 15) * 32, n0 = (rem >> 4) * 32;
        int tx = tid & 31, ty = tid >> 5;
        float (*t)[33] = (float (*)[33])eb;
#pragma unroll
        for (int q = 0; q < 4; q++)
            t[ty + q * 8][tx] = W[(size_t)(k0 + ty + q * 8) * DD + n0 + tx];
        __syncthreads();
#pragma unroll
        for (int q = 0; q < 4; q++)
            T[(size_t)(nbase + n0 + ty + q * 8) * DD + k0 + tx] = f2bf(t[tx][ty + q * 8]);
    } else {
        int idx = u - 4864;
        int b = idx >> 3, k = idx & 7;
#pragma unroll
        for (int q = 0; q < 2; q++) {
            int d = tid + q * 256;
            float sg = expf(p.slots_logsg[k * DD + d]);
            float sl = fmaf(sg, p.noise_init[((size_t)(b * KK + k)) * DD + d],
                            p.slots_mu[k * DD + d]);
            p.slotbf[((size_t)(b * KK + k)) * DD + d] = f2bf(sl);
        }
    }
}

// ===========================================================================
// 2) gemm: u in [0,1032) : 128x128 MFMA GEMM (round-12, measured best):
//    LDS staging + register-prefetch pipeline + XCD swizzle; single-pass
//    coalesced epilogue (x<4 -> Kbf, x>=4 -> Vbf, u>=1024 -> queries).
// ===========================================================================
__global__ __launch_bounds__(256) void k_gemm(Params p)
{
    __shared__ __align__(16) short smem[16384];   // 32 KB: As | Bs
    int u = blockIdx.x, tid = threadIdx.x;
    int w = tid >> 6, l = tid & 63;
    int x, by, qmode;
    if (u >= 1024) { qmode = 1; x = u - 1024; if (x >= 4) return; by = 128; }
    else           { qmode = 0; x = u >> 7;   by = u & 127; }
    const short* A  = qmode ? p.slotbf : p.Abf + (size_t)by * 128 * DD;
    const short* Bt = qmode ? p.WqT : p.WtKV;
    int row0 = qmode ? 0 : by * 128;
    int col0 = x * 128;

    short* As = smem;
    short* Bs = smem + 8192;
    int sr = l >> 3;
    int sg_off = ((l & 7) ^ sr) * 8;
    int mq = (w & 1) * 64, nq = (w >> 1) * 64;
    int fr = l & 15;
    int orow = (l >> 4) * 4, ocol = l & 15;

    int4v ra[4], rb4[4];
    auto LOADR = [&](int k0) {
#pragma unroll
        for (int j = 0; j < 4; j++) {
            int rbj = w * 32 + j * 8;
            int r   = rbj + sr;
            ra[j]  = *(const int4v*)(A  + (size_t)r * DD + k0 + sg_off);
            rb4[j] = *(const int4v*)(Bt + (size_t)(col0 + r) * DD + k0 + sg_off);
        }
    };
    auto WRITES = [&]() {
#pragma unroll
        for (int j = 0; j < 4; j++) {
            int rbj = w * 32 + j * 8;
            *(int4v*)&As[rbj * 64 + l * 8] = ra[j];
            *(int4v*)&Bs[rbj * 64 + l * 8] = rb4[j];
        }
    };

    f32x4 acc[4][4] = {};
    LOADR(0);
    WRITES();
    __syncthreads();
    for (int i = 0; i < 8; i++) {
        if (i < 7) LOADR((i + 1) * 64);
#pragma unroll
        for (int kk = 0; kk < 2; kk++) {
            int g = kk * 4 + (l >> 4);
            short8 af[4], bfv[4];
#pragma unroll
            for (int mi = 0; mi < 4; mi++)
                af[mi] = *(const short8*)&As[(mq + mi * 16 + fr) * 64 + (g ^ (fr & 7)) * 8];
#pragma unroll
            for (int ni = 0; ni < 4; ni++)
                bfv[ni] = *(const short8*)&Bs[(nq + ni * 16 + fr) * 64 + (g ^ (fr & 7)) * 8];
#pragma unroll
            for (int mi = 0; mi < 4; mi++)
#pragma unroll
                for (int ni = 0; ni < 4; ni++)
                    acc[mi][ni] = __builtin_amdgcn_mfma_f32_16x16x32_bf16(
                        af[mi], bfv[ni], acc[mi][ni], 0, 0, 0);
        }
        __syncthreads();
        if (i < 7) {
            WRITES();
            __syncthreads();
        }
    }

    float bvv[4];
#pragma unroll
    for (int ni = 0; ni < 4; ni++) {
        int col = col0 + nq + ni * 16 + ocol;
        bvv[ni] = qmode ? p.bq[col] : (x < 4 ? p.bk[col] : p.bv[col - 512]);
    }

    if (qmode) {
#pragma unroll
        for (int ni = 0; ni < 4; ni++) {
            int col = col0 + nq + ni * 16 + ocol;
#pragma unroll
            for (int mi = 0; mi < 4; mi++)
#pragma unroll
                for (int r = 0; r < 4; r++)
                    p.queries[(size_t)(mq + mi * 16 + orow + r) * DD + col] =
                        acc[mi][ni][r] + bvv[ni];
        }
    } else {
        short* eb = smem;   // 32 KB epilogue buffer
        short* dst = (x < 4) ? p.Kbf : p.Vbf;
        int ccol0 = (x & 3) * 128;
#pragma unroll
        for (int mi = 0; mi < 4; mi++)
#pragma unroll
            for (int r = 0; r < 4; r++) {
                int row = mq + mi * 16 + orow + r;
                int sw = ((row >> 2) & 3) << 1;
#pragma unroll
                for (int ni = 0; ni < 4; ni++) {
                    int colg = nq + ni * 16 + ocol;
                    eb[row * 128 + (((colg >> 3) ^ sw) * 8) + (colg & 7)] =
                        f2bf(acc[mi][ni][r] + bvv[ni]);
                }
            }
        __syncthreads();
#pragma unroll
        for (int i = 0; i < 8; i++) {
            int row = i * 16 + w * 4 + (l >> 4);
            int c = l & 15;
            int cc = c ^ (((row >> 2) & 3) << 1);
            short8 vv = *(const short8*)&eb[row * 128 + cc * 8];
            *(short8*)&dst[(size_t)(row0 + row) * 512 + ccol0 + c * 8] = vv;
        }
    }
}

// ===========================================================================
// 3) fprep0: u in [0,256) : initial F/off/mix + colsum & counter reset
//    (verified rounds 7-13)
// ===========================================================================
__global__ __launch_bounds__(256) void k_fprep0(Params p)
{
    __shared__ float red[512];
    int u = blockIdx.x, tid = threadIdx.x;
    int b = u >> 4, k = u & 15;
    if (u < 16 && tid == 0) p.cnt[u] = 0;
    short* Fr = p.F_bt + (size_t)(b * 16 + k) * 1024;
    if (k >= KK) {
        short4v zv = {0, 0, 0, 0};
        *(short4v*)&Fr[tid * 4] = zv;
        if (tid == 0) { p.off[b * 16 + k] = 0.0f; p.mix16[b * 16 + k] = 0.0f; }
        return;
    }
    float* rc = red;
    float* rl = red + 256;
    float c = 0.0f, ld = 0.0f;
#pragma unroll
    for (int q = 0; q < 2; q++) {
        int d = tid * 2 + q;
        float sg = expf(p.slots_logsg[k * DD + d]);
        float iv = 1.0f / (sg * sg + EPS_);
        float qv = p.queries[((size_t)(b * KK + k)) * DD + d];
        Fr[d]       = f2bf(-0.5f * iv);
        Fr[512 + d] = f2bf(qv * iv);
        c  = fmaf(qv * qv, iv, c);
        ld += logf(fabsf(sg) + EPS_);
    }
    rc[tid] = c; rl[tid] = ld;
    __syncthreads();
    for (int s = 128; s > 0; s >>= 1) {
        if (tid < s) { rc[tid] += rc[tid + s]; rl[tid] += rl[tid + s]; }
        __syncthreads();
    }
    if (tid == 0) {
        p.off[b * 16 + k]    = GLL_C0 - 0.5f * rl[0] - 0.5f * rc[0];
        p.mix16[b * 16 + k]  = p.mixing_co[k];
        p.colsum[b * KK + k] = 0.0f;
    }
}

// ===========================================================================
// 4) FUSED gll + musigma + (last-block-per-b) fprep/final.
//    Identical numerics to round 13 (verified); tail loops restructured for
//    memory-level parallelism (ns outer / k inner-unrolled: 16 independent
//    loads per step, x4 unroll -> ~64 outstanding; round-13 tail was serial).
// ===========================================================================
__global__ __launch_bounds__(512) void k_gllmu(Params p, int mode)
{
    __shared__ f32x4 red[3][2][64];   // 6 KB
    __shared__ float asml[32 * KK];   // 1 KB
    __shared__ float redk[2][8][8];   // 512 B
    __shared__ int lastS;
    int u = blockIdx.x, tid = threadIdx.x;
    int w = tid >> 6, l = tid & 63;
    int b = u >> 5, chunk = u & 31;
    int n0 = chunk * 32;
    int t = w & 1, ks = w >> 1;       // row-tile, K-split (0..3)

    // ---- phase A ----
    const short* Ka = p.Kbf + ((size_t)(b * NN + n0 + t * 16 + (l & 15))) * 512
                      + ks * 128 + (l >> 4) * 8;
    const short* Fi = p.F_bt + (size_t)(b * 16 + (l & 15)) * 1024
                      + ks * 128 + (l >> 4) * 8;
    f32x4 acc0 = {}, acc1 = {};
#pragma unroll
    for (int j = 0; j < 4; j++) {
        short8 kf = *(const short8*)&Ka[j * 32];
        short8 f0 = *(const short8*)&Fi[j * 32];         // -0.5*invvar
        short8 f1 = *(const short8*)&Fi[j * 32 + 512];   // q*invvar
        short8 k2;
#pragma unroll
        for (int e = 0; e < 8; e++) {
            float kv = bf2f(kf[e]);
            k2[e] = f2bf(kv * kv);
        }
        acc0 = __builtin_amdgcn_mfma_f32_16x16x32_bf16(k2, f0, acc0, 0, 0, 0);
        acc1 = __builtin_amdgcn_mfma_f32_16x16x32_bf16(kf, f1, acc1, 0, 0, 0);
    }
    f32x4 acc = acc0 + acc1;

    if (ks) red[ks - 1][t][l] = acc;
    __syncthreads();
    if (ks == 0) {
#pragma unroll
        for (int i = 0; i < 3; i++) acc += red[i][t][l];
        int col = l & 15;
        int rloc = t * 16 + (l >> 4) * 4;
        float offv = p.off[b * 16 + col];
        float mixv = p.mix16[b * 16 + col];
        float a[4], den[4];
#pragma unroll
        for (int r = 0; r < 4; r++) {
            a[r] = mixv * (acc[r] + offv);
            den[r] = a[r];
        }
#pragma unroll
        for (int mask = 1; mask <= 8; mask <<= 1)
#pragma unroll
            for (int r = 0; r < 4; r++) den[r] += __shfl_xor(den[r], mask);
        float csl = 0.0f;
        if (col < KK) {
#pragma unroll
            for (int r = 0; r < 4; r++) {
                float vv = a[r] / den[r];
                asml[(rloc + r) * KK + col] = vv;
                if (mode) p.attn[((size_t)(b * NN + n0 + rloc + r)) * KK + col] = vv;
                csl += vv;
            }
        }
        csl += __shfl_xor(csl, 16);
        csl += __shfl_xor(csl, 32);
        if (l < KK) atomicAdd(&p.colsum[b * KK + l], csl);
    }
    __syncthreads();

    // ---- phase B: 512 threads, one d-column each over 32 rows ----
    {
        float s1[KK] = {}, s2[KK] = {};
        const short* vb = p.Vbf + ((size_t)(b * NN + n0)) * DD + tid;
#pragma unroll 4
        for (int nn = 0; nn < 32; nn++) {
            float v = bf2f(vb[(size_t)nn * DD]);
            float vq = v * v;
            float4 a0 = *(const float4*)&asml[nn * KK];
            float4 a1 = *(const float4*)&asml[nn * KK + 4];
            float aa[8] = {a0.x, a0.y, a0.z, a0.w, a1.x, a1.y, a1.z, a1.w};
#pragma unroll
            for (int k = 0; k < KK; k++) {
                s1[k] = fmaf(aa[k], v, s1[k]);
                s2[k] = fmaf(aa[k], vq, s2[k]);
            }
        }
        size_t base = ((size_t)(b * 32 + chunk) * KK) * DD + tid;
#pragma unroll
        for (int k = 0; k < KK; k++) {
            p.s1p[base + (size_t)k * DD] = s1[k];
            p.s2p[base + (size_t)k * DD] = s2[k];
        }
    }

    // ---- last-block-per-b epilogue ----
    __threadfence();
    __syncthreads();
    if (tid == 0) lastS = (atomicAdd(&p.cnt[b], 1) == 31) ? 1 : 0;
    __syncthreads();
    if (!lastS) return;
    __threadfence();   // acquire: see all 32 blocks' s1p/s2p/colsum/attn
    if (tid == 0) p.cnt[b] = 0;

    int d = tid;       // 512 threads = 512 d columns
    float csv[KK], invv[KK], ssv[KK];
#pragma unroll
    for (int k = 0; k < KK; k++) {
        csv[k]  = p.colsum[b * KK + k];
        invv[k] = 1.0f / (csv[k] + EPS_);
        ssv[k]  = csv[k] * invv[k];
    }

    // ILP-friendly partial reduction: ns outer (x4 unroll), k inner-unrolled
    // -> 16 independent loads per step, ~64 outstanding.
    float s1a[KK] = {}, s2a[KK] = {};
#pragma unroll 4
    for (int ns = 0; ns < 32; ns++) {
        size_t o0 = ((size_t)(b * 32 + ns) * KK) * DD + d;
#pragma unroll
        for (int k = 0; k < KK; k++) {
            s1a[k] += p.s1p[o0 + (size_t)k * DD];
            s2a[k] += p.s2p[o0 + (size_t)k * DD];
        }
    }

    if (mode == 0) {
        float ck[KK], lk[KK];
#pragma unroll
        for (int k = 0; k < KK; k++) {
            float m  = s1a[k] * invv[k];
            float sg = s2a[k] * invv[k] - m * m * (2.0f - ssv[k]);
            float iv = 1.0f / (sg * sg + EPS_);
            float qv = p.queries[((size_t)(b * KK + k)) * DD + d];
            short* Fr = p.F_bt + (size_t)(b * 16 + k) * 1024;
            Fr[d]       = f2bf(-0.5f * iv);
            Fr[512 + d] = f2bf(qv * iv);
            ck[k] = qv * qv * iv;
            lk[k] = logf(fabsf(sg) + EPS_);
        }
        // reduce ck/lk per k across 512 threads
        int wv = tid >> 6, ln = tid & 63;
#pragma unroll
        for (int k = 0; k < KK; k++) {
            float cv = ck[k], lv = lk[k];
#pragma unroll
            for (int off = 32; off; off >>= 1) {
                cv += __shfl_xor(cv, off);
                lv += __shfl_xor(lv, off);
            }
            if (ln == 0) { redk[0][wv][k] = cv; redk[1][wv][k] = lv; }
        }
        __syncthreads();
        if (tid < KK) {
            float cs_ = 0.0f, ls_ = 0.0f;
#pragma unroll
            for (int wv2 = 0; wv2 < 8; wv2++) {
                cs_ += redk[0][wv2][tid];
                ls_ += redk[1][wv2][tid];
            }
            p.off[b * 16 + tid]    = GLL_C0 - 0.5f * ls_ - 0.5f * cs_;
            p.mix16[b * 16 + tid]  = ssv[tid] * (1.0f / NN);
            p.colsum[b * KK + tid] = 0.0f;
        }
    } else {
        // slots out (independent loads per k — good ILP)
        float nf[KK];
#pragma unroll
        for (int k = 0; k < KK; k++)
            nf[k] = p.noise_final[(b * KK + k) * DD + d];
#pragma unroll
        for (int k = 0; k < KK; k++) {
            float m  = s1a[k] * invv[k];
            float sg = s2a[k] * invv[k] - m * m * (2.0f - ssv[k]);
            p.out[(b * KK + k) * DD + d] = fmaf(fmaxf(fabsf(sg), EPS_), nf[k], m);
        }
        // attn^T out for this b: 8192 elems / 512 threads = 16 each
#pragma unroll 4
        for (int i = 0; i < 16; i++) {
            int idx = i * 512 + tid;         // k*1024 + n
            int k = idx >> 10, n = idx & 1023;
            p.out[BB * KK * DD + (b * KK + k) * 1024 + n] =
                p.attn[((size_t)(b * NN + n)) * KK + k] / (csv[k] + EPS_);
        }
    }
}

// ===========================================================================
extern "C" void kernel_launch(void* const* d_in, const int* in_sizes, int n_in,
                              void* d_out, int out_size, void* d_ws, size_t ws_size,
                              hipStream_t stream)
{
    Params pp;
    pp.emb         = (const float*)d_in[0];
    pp.noise_init  = (const float*)d_in[1];
    pp.noise_final = (const float*)d_in[2];
    pp.slots_mu    = (const float*)d_in[3];
    pp.slots_logsg = (const float*)d_in[4];
    pp.mixing_co   = (const float*)d_in[5];
    pp.Wk          = (const float*)d_in[6];
    pp.bk          = (const float*)d_in[7];
    pp.Wq          = (const float*)d_in[8];
    pp.bq          = (const float*)d_in[9];
    pp.Wv          = (const float*)d_in[10];
    pp.bv          = (const float*)d_in[11];
    pp.ln_g        = (const float*)d_in[12];
    pp.ln_b        = (const float*)d_in[13];
    pp.out         = (float*)d_out;

    float* ws = (float*)d_ws;
    pp.queries = ws;
    pp.attn    = pp.queries + BB * KK * DD;
    pp.s1p     = pp.attn + BB * NN * KK;
    pp.s2p     = pp.s1p + (size_t)BB * 32 * KK * DD;
    pp.off     = pp.s2p + (size_t)BB * 32 * KK * DD;
    pp.mix16   = pp.off + BB * 16;
    pp.colsum  = pp.mix16 + BB * 16;
    pp.cnt     = (int*)(pp.colsum + BB * KK);
    pp.Abf     = (short*)(pp.cnt + 64);
    pp.Kbf     = pp.Abf + (size_t)BB * NN * DD;
    pp.Vbf     = pp.Kbf + (size_t)BB * NN * DD;
    pp.WtKV    = pp.Vbf + (size_t)BB * NN * DD;
    pp.WqT     = pp.WtKV + (size_t)1024 * DD;
    pp.slotbf  = pp.WqT + (size_t)DD * DD;
    pp.F_bt    = pp.slotbf + (size_t)BB * KK * DD;

    k_pre<<<4992, 256, 0, stream>>>(pp);
    k_gemm<<<1032, 256, 0, stream>>>(pp);
    k_fprep0<<<256, 256, 0, stream>>>(pp);
    for (int it = 0; it < 3; it++)
        k_gllmu<<<512, 512, 0, stream>>>(pp, it == 2 ? 1 : 0);
}

// Round 15
// 199.918 us; speedup vs baseline: 3.2926x; 3.0951x over previous
//
#include <hip/hip_runtime.h>
#include <math.h>

// Problem constants
#define BB 16
#define NN 1024
#define DD 512
#define KK 8
#define EPS_ 1e-8f
#define LN_EPS_ 1e-5f
// -0.5 * D * log(2*pi)
#define GLL_C0 (-470.4965290007924f)

typedef __attribute__((ext_vector_type(8))) short short8;
typedef __attribute__((ext_vector_type(4))) short short4v;
typedef __attribute__((ext_vector_type(4))) float f32x4;
typedef __attribute__((ext_vector_type(4))) int int4v;

static __device__ inline short f2bf(float f) {
    unsigned u = __builtin_bit_cast(unsigned, f);
    u = (u + 0x7fff + ((u >> 16) & 1)) >> 16;
    return (short)u;
}
static __device__ inline float bf2f(short s) {
    unsigned u = ((unsigned)(unsigned short)s) << 16;
    return __builtin_bit_cast(float, u);
}

struct Params {
    const float *emb, *noise_init, *noise_final, *slots_mu, *slots_logsg,
                *mixing_co, *Wk, *bk, *Wq, *bq, *Wv, *bv, *ln_g, *ln_b;
    float *out;
    float *queries, *attn, *s1p, *s2p, *off, *mix16, *colsum;
    short *Abf, *Kbf, *Vbf, *WtKV, *WqT, *slotbf, *F_bt;
};

// ===========================================================================
// 1) pre: u in [0,4992) : LN+cast | weight transpose | slot init
//    (verified correct rounds 7-14)
// ===========================================================================
__global__ __launch_bounds__(256) void k_pre(Params p)
{
    __shared__ __align__(16) short eb[4352];
    int u = blockIdx.x, tid = threadIdx.x;
    if (u < 4096) {
        int row  = u * 4 + (tid >> 6);
        int lane = tid & 63;
        const float* e = p.emb + (size_t)row * DD + lane * 8;
        float4 v0 = *(const float4*)e;
        float4 v1 = *(const float4*)(e + 4);
        float v[8] = {v0.x, v0.y, v0.z, v0.w, v1.x, v1.y, v1.z, v1.w};
        float s = 0.0f;
#pragma unroll
        for (int j = 0; j < 8; j++) s += v[j];
#pragma unroll
        for (int off = 32; off; off >>= 1) s += __shfl_xor(s, off);
        float m = s * (1.0f / DD);
        float vs = 0.0f;
#pragma unroll
        for (int j = 0; j < 8; j++) { float d = v[j] - m; vs = fmaf(d, d, vs); }
#pragma unroll
        for (int off = 32; off; off >>= 1) vs += __shfl_xor(vs, off);
        float rstd = rsqrtf(vs * (1.0f / DD) + LN_EPS_);

        float4 g0 = *(const float4*)&p.ln_g[lane * 8];
        float4 g1 = *(const float4*)&p.ln_g[lane * 8 + 4];
        float4 b0 = *(const float4*)&p.ln_b[lane * 8];
        float4 b1 = *(const float4*)&p.ln_b[lane * 8 + 4];
        float g[8] = {g0.x, g0.y, g0.z, g0.w, g1.x, g1.y, g1.z, g1.w};
        float bb[8] = {b0.x, b0.y, b0.z, b0.w, b1.x, b1.y, b1.z, b1.w};
        short8 o;
#pragma unroll
        for (int j = 0; j < 8; j++) o[j] = f2bf(fmaf((v[j] - m) * rstd, g[j], bb[j]));
        *(short8*)&p.Abf[(size_t)row * DD + lane * 8] = o;
    } else if (u < 4864) {
        int idx = u - 4096;
        int z = idx >> 8, rem = idx & 255;
        const float* W = (z == 0) ? p.Wk : (z == 1) ? p.Wv : p.Wq;
        short* T; int nbase;
        if (z < 2) { T = p.WtKV; nbase = z * 512; } else { T = p.WqT; nbase = 0; }
        int k0 = (rem & 15) * 32, n0 = (rem >> 4) * 32;
        int tx = tid & 31, ty = tid >> 5;
        float (*t)[33] = (float (*)[33])eb;
#pragma unroll
        for (int q = 0; q < 4; q++)
            t[ty + q * 8][tx] = W[(size_t)(k0 + ty + q * 8) * DD + n0 + tx];
        __syncthreads();
#pragma unroll
        for (int q = 0; q < 4; q++)
            T[(size_t)(nbase + n0 + ty + q * 8) * DD + k0 + tx] = f2bf(t[tx][ty + q * 8]);
    } else {
        int idx = u - 4864;
        int b = idx >> 3, k = idx & 7;
#pragma unroll
        for (int q = 0; q < 2; q++) {
            int d = tid + q * 256;
            float sg = expf(p.slots_logsg[k * DD + d]);
            float sl = fmaf(sg, p.noise_init[((size_t)(b * KK + k)) * DD + d],
                            p.slots_mu[k * DD + d]);
            p.slotbf[((size_t)(b * KK + k)) * DD + d] = f2bf(sl);
        }
    }
}

// ===========================================================================
// 2) gemm: u in [0,1032) : 128x128 MFMA GEMM.
//    LDS DOUBLE-BUFFER (64 KB) + register prefetch + ONE barrier per K-iter:
//    compute(buf i) runs while global loads for i+1 are in flight to VGPRs;
//    ds_write goes to buf (i+1)&1 BEFORE the barrier (that buffer was last
//    read before the previous barrier -> race-free).  vmcnt waits land at
//    the ds_write, after compute.  XCD swizzle (x=u>>7, by=u&127) keeps the
//    8 col-blocks sharing an A-tile on one XCD's L2.  Single-pass coalesced
//    epilogue: x<4 -> Kbf, x>=4 -> Vbf, u>=1024 -> queries (fp32).
// ===========================================================================
__global__ __launch_bounds__(256) void k_gemm(Params p)
{
    __shared__ __align__(16) short smem[32768];   // 64 KB: As0|As1|Bs0|Bs1
    int u = blockIdx.x, tid = threadIdx.x;
    int w = tid >> 6, l = tid & 63;
    int x, by, qmode;
    if (u >= 1024) { qmode = 1; x = u - 1024; if (x >= 4) return; by = 128; }
    else           { qmode = 0; x = u >> 7;   by = u & 127; }
    const short* A  = qmode ? p.slotbf : p.Abf + (size_t)by * 128 * DD;
    const short* Bt = qmode ? p.WqT : p.WtKV;
    int row0 = qmode ? 0 : by * 128;
    int col0 = x * 128;

    int sr = l >> 3;
    int sg_off = ((l & 7) ^ sr) * 8;
    int mq = (w & 1) * 64, nq = (w >> 1) * 64;
    int fr = l & 15;
    int orow = (l >> 4) * 4, ocol = l & 15;

    int4v ra[4], rb4[4];
    auto LOADR = [&](int k0) {
#pragma unroll
        for (int j = 0; j < 4; j++) {
            int rbj = w * 32 + j * 8;
            int r   = rbj + sr;
            ra[j]  = *(const int4v*)(A  + (size_t)r * DD + k0 + sg_off);
            rb4[j] = *(const int4v*)(Bt + (size_t)(col0 + r) * DD + k0 + sg_off);
        }
    };
    auto WRITES = [&](int buf) {
        short* As_ = smem + buf * 8192;
        short* Bs_ = smem + 16384 + buf * 8192;
#pragma unroll
        for (int j = 0; j < 4; j++) {
            int rbj = w * 32 + j * 8;
            *(int4v*)&As_[rbj * 64 + l * 8] = ra[j];
            *(int4v*)&Bs_[rbj * 64 + l * 8] = rb4[j];
        }
    };

    f32x4 acc[4][4] = {};
    LOADR(0);
    WRITES(0);
    __syncthreads();
    for (int i = 0; i < 8; i++) {
        if (i < 7) LOADR((i + 1) * 64);   // in flight during compute
        const short* As_ = smem + (i & 1) * 8192;
        const short* Bs_ = smem + 16384 + (i & 1) * 8192;
#pragma unroll
        for (int kk = 0; kk < 2; kk++) {
            int g = kk * 4 + (l >> 4);
            short8 af[4], bfv[4];
#pragma unroll
            for (int mi = 0; mi < 4; mi++)
                af[mi] = *(const short8*)&As_[(mq + mi * 16 + fr) * 64 + (g ^ (fr & 7)) * 8];
#pragma unroll
            for (int ni = 0; ni < 4; ni++)
                bfv[ni] = *(const short8*)&Bs_[(nq + ni * 16 + fr) * 64 + (g ^ (fr & 7)) * 8];
#pragma unroll
            for (int mi = 0; mi < 4; mi++)
#pragma unroll
                for (int ni = 0; ni < 4; ni++)
                    acc[mi][ni] = __builtin_amdgcn_mfma_f32_16x16x32_bf16(
                        af[mi], bfv[ni], acc[mi][ni], 0, 0, 0);
        }
        if (i < 7) WRITES((i + 1) & 1);   // vmcnt wait here, hidden by compute
        __syncthreads();                  // ONE barrier per iteration
    }

    float bvv[4];
#pragma unroll
    for (int ni = 0; ni < 4; ni++) {
        int col = col0 + nq + ni * 16 + ocol;
        bvv[ni] = qmode ? p.bq[col] : (x < 4 ? p.bk[col] : p.bv[col - 512]);
    }

    if (qmode) {
#pragma unroll
        for (int ni = 0; ni < 4; ni++) {
            int col = col0 + nq + ni * 16 + ocol;
#pragma unroll
            for (int mi = 0; mi < 4; mi++)
#pragma unroll
                for (int r = 0; r < 4; r++)
                    p.queries[(size_t)(mq + mi * 16 + orow + r) * DD + col] =
                        acc[mi][ni][r] + bvv[ni];
        }
    } else {
        short* eb = smem;   // epilogue buffer (first 32 KB)
        short* dst = (x < 4) ? p.Kbf : p.Vbf;
        int ccol0 = (x & 3) * 128;
#pragma unroll
        for (int mi = 0; mi < 4; mi++)
#pragma unroll
            for (int r = 0; r < 4; r++) {
                int row = mq + mi * 16 + orow + r;
                int sw = ((row >> 2) & 3) << 1;
#pragma unroll
                for (int ni = 0; ni < 4; ni++) {
                    int colg = nq + ni * 16 + ocol;
                    eb[row * 128 + (((colg >> 3) ^ sw) * 8) + (colg & 7)] =
                        f2bf(acc[mi][ni][r] + bvv[ni]);
                }
            }
        __syncthreads();
#pragma unroll
        for (int i = 0; i < 8; i++) {
            int row = i * 16 + w * 4 + (l >> 4);
            int c = l & 15;
            int cc = c ^ (((row >> 2) & 3) << 1);
            short8 vv = *(const short8*)&eb[row * 128 + cc * 8];
            *(short8*)&dst[(size_t)(row0 + row) * 512 + ccol0 + c * 8] = vv;
        }
    }
}

// ===========================================================================
// 3) fprep0: u in [0,256)  (verified rounds 7-14)
// ===========================================================================
__global__ __launch_bounds__(256) void k_fprep0(Params p)
{
    __shared__ float red[512];
    int u = blockIdx.x, tid = threadIdx.x;
    int b = u >> 4, k = u & 15;
    short* Fr = p.F_bt + (size_t)(b * 16 + k) * 1024;
    if (k >= KK) {
        short4v zv = {0, 0, 0, 0};
        *(short4v*)&Fr[tid * 4] = zv;
        if (tid == 0) { p.off[b * 16 + k] = 0.0f; p.mix16[b * 16 + k] = 0.0f; }
        return;
    }
    float* rc = red;
    float* rl = red + 256;
    float c = 0.0f, ld = 0.0f;
#pragma unroll
    for (int q = 0; q < 2; q++) {
        int d = tid * 2 + q;
        float sg = expf(p.slots_logsg[k * DD + d]);
        float iv = 1.0f / (sg * sg + EPS_);
        float qv = p.queries[((size_t)(b * KK + k)) * DD + d];
        Fr[d]       = f2bf(-0.5f * iv);
        Fr[512 + d] = f2bf(qv * iv);
        c  = fmaf(qv * qv, iv, c);
        ld += logf(fabsf(sg) + EPS_);
    }
    rc[tid] = c; rl[tid] = ld;
    __syncthreads();
    for (int s = 128; s > 0; s >>= 1) {
        if (tid < s) { rc[tid] += rc[tid + s]; rl[tid] += rl[tid + s]; }
        __syncthreads();
    }
    if (tid == 0) {
        p.off[b * 16 + k]    = GLL_C0 - 0.5f * rl[0] - 0.5f * rc[0];
        p.mix16[b * 16 + k]  = p.mixing_co[k];
        p.colsum[b * KK + k] = 0.0f;
    }
}

// ===========================================================================
// 4) FUSED gll + musigma, 32-row chunks, 512 threads (round-12, verified,
//    measured <41 us): 8 waves = 2 row-tiles x 4 K-splits, keys squared on
//    the fly, LDS reduce, normalize, colsum atomics; phase B 1 d/thread.
// ===========================================================================
__global__ __launch_bounds__(512) void k_gllmu(Params p)
{
    __shared__ f32x4 red[3][2][64];   // 6 KB
    __shared__ float asml[32 * KK];   // 1 KB
    int u = blockIdx.x, tid = threadIdx.x;
    int w = tid >> 6, l = tid & 63;
    int b = u >> 5, chunk = u & 31;
    int n0 = chunk * 32;
    int t = w & 1, ks = w >> 1;       // row-tile, K-split (0..3)

    // ---- phase A ----
    const short* Ka = p.Kbf + ((size_t)(b * NN + n0 + t * 16 + (l & 15))) * 512
                      + ks * 128 + (l >> 4) * 8;
    const short* Fi = p.F_bt + (size_t)(b * 16 + (l & 15)) * 1024
                      + ks * 128 + (l >> 4) * 8;
    f32x4 acc0 = {}, acc1 = {};
#pragma unroll
    for (int j = 0; j < 4; j++) {
        short8 kf = *(const short8*)&Ka[j * 32];
        short8 f0 = *(const short8*)&Fi[j * 32];         // -0.5*invvar
        short8 f1 = *(const short8*)&Fi[j * 32 + 512];   // q*invvar
        short8 k2;
#pragma unroll
        for (int e = 0; e < 8; e++) {
            float kv = bf2f(kf[e]);
            k2[e] = f2bf(kv * kv);
        }
        acc0 = __builtin_amdgcn_mfma_f32_16x16x32_bf16(k2, f0, acc0, 0, 0, 0);
        acc1 = __builtin_amdgcn_mfma_f32_16x16x32_bf16(kf, f1, acc1, 0, 0, 0);
    }
    f32x4 acc = acc0 + acc1;

    if (ks) red[ks - 1][t][l] = acc;
    __syncthreads();
    if (ks == 0) {
#pragma unroll
        for (int i = 0; i < 3; i++) acc += red[i][t][l];
        int col = l & 15;
        int rloc = t * 16 + (l >> 4) * 4;
        float offv = p.off[b * 16 + col];
        float mixv = p.mix16[b * 16 + col];
        float a[4], den[4];
#pragma unroll
        for (int r = 0; r < 4; r++) {
            a[r] = mixv * (acc[r] + offv);
            den[r] = a[r];
        }
#pragma unroll
        for (int mask = 1; mask <= 8; mask <<= 1)
#pragma unroll
            for (int r = 0; r < 4; r++) den[r] += __shfl_xor(den[r], mask);
        float csl = 0.0f;
        if (col < KK) {
#pragma unroll
            for (int r = 0; r < 4; r++) {
                float vv = a[r] / den[r];
                asml[(rloc + r) * KK + col] = vv;
                p.attn[((size_t)(b * NN + n0 + rloc + r)) * KK + col] = vv;
                csl += vv;
            }
        }
        csl += __shfl_xor(csl, 16);
        csl += __shfl_xor(csl, 32);
        if (l < KK) atomicAdd(&p.colsum[b * KK + l], csl);
    }
    __syncthreads();

    // ---- phase B: 512 threads, one d-column each over 32 rows ----
    float s1[KK] = {}, s2[KK] = {};
    const short* vb = p.Vbf + ((size_t)(b * NN + n0)) * DD + tid;
#pragma unroll 4
    for (int nn = 0; nn < 32; nn++) {
        float v = bf2f(vb[(size_t)nn * DD]);
        float vq = v * v;
        float4 a0 = *(const float4*)&asml[nn * KK];
        float4 a1 = *(const float4*)&asml[nn * KK + 4];
        float aa[8] = {a0.x, a0.y, a0.z, a0.w, a1.x, a1.y, a1.z, a1.w};
#pragma unroll
        for (int k = 0; k < KK; k++) {
            s1[k] = fmaf(aa[k], v, s1[k]);
            s2[k] = fmaf(aa[k], vq, s2[k]);
        }
    }
    size_t base = ((size_t)(b * 32 + chunk) * KK) * DD + tid;
#pragma unroll
    for (int k = 0; k < KK; k++) {
        p.s1p[base + (size_t)k * DD] = s1[k];
        p.s2p[base + (size_t)k * DD] = s2[k];
    }
}

// ===========================================================================
// 5) fprep: u in [0,128)  (verified rounds 9-12)
// ===========================================================================
__global__ __launch_bounds__(256) void k_fprep(Params p)
{
    __shared__ float red[512];
    int u = blockIdx.x, tid = threadIdx.x;
    int b = u >> 3, k = u & 7;
    float cs   = p.colsum[b * KK + k];
    float inv  = 1.0f / (cs + EPS_);
    float ssum = cs * inv;
    short* Fr = p.F_bt + (size_t)(b * 16 + k) * 1024;
    float* rc = red;
    float* rl = red + 256;
    float c = 0.0f, ld = 0.0f;
#pragma unroll
    for (int q = 0; q < 2; q++) {
        int d = tid * 2 + q;
        float s1 = 0.0f, s2 = 0.0f;
#pragma unroll
        for (int ns = 0; ns < 32; ns++) {
            size_t o = ((size_t)(b * 32 + ns) * KK + k) * DD + d;
            s1 += p.s1p[o];
            s2 += p.s2p[o];
        }
        float m  = s1 * inv;
        float sg = s2 * inv - m * m * (2.0f - ssum);
        float iv = 1.0f / (sg * sg + EPS_);
        float qv = p.queries[((size_t)(b * KK + k)) * DD + d];
        Fr[d]       = f2bf(-0.5f * iv);
        Fr[512 + d] = f2bf(qv * iv);
        c  = fmaf(qv * qv, iv, c);
        ld += logf(fabsf(sg) + EPS_);
    }
    rc[tid] = c; rl[tid] = ld;
    __syncthreads();
    for (int s = 128; s > 0; s >>= 1) {
        if (tid < s) { rc[tid] += rc[tid + s]; rl[tid] += rl[tid + s]; }
        __syncthreads();
    }
    if (tid == 0) {
        p.off[b * 16 + k]    = GLL_C0 - 0.5f * rl[0] - 0.5f * rc[0];
        p.mix16[b * 16 + k]  = ssum * (1.0f / NN);
        p.colsum[b * KK + k] = 0.0f;
    }
}

// ===========================================================================
// 6) final: u in [0,768)  (verified rounds 9-12)
// ===========================================================================
__global__ __launch_bounds__(256) void k_final(Params p)
{
    int u = blockIdx.x, tid = threadIdx.x;
    if (u < 256) {
        int gid = u * 256 + tid;
        int d = gid & 511;
        int k = (gid >> 9) & 7;
        int b = gid >> 12;
        float s1 = 0.0f, s2 = 0.0f;
#pragma unroll
        for (int ns = 0; ns < 32; ns++) {
            size_t o = ((size_t)(b * 32 + ns) * KK + k) * DD + d;
            s1 += p.s1p[o];
            s2 += p.s2p[o];
        }
        float cs   = p.colsum[b * KK + k];
        float inv  = 1.0f / (cs + EPS_);
        float ssum = cs * inv;
        float m    = s1 * inv;
        float sg   = s2 * inv - m * m * (2.0f - ssum);
        p.out[gid] = fmaf(fmaxf(fabsf(sg), EPS_), p.noise_final[gid], m);
    } else {
        int gid = (u - 256) * 256 + tid;
        int b = gid >> 13;
        int k = (gid >> 10) & 7;
        int n = gid & 1023;
        float cs = p.colsum[b * KK + k];
        p.out[BB * KK * DD + gid] =
            p.attn[((size_t)(b * NN + n)) * KK + k] / (cs + EPS_);
    }
}

// ===========================================================================
extern "C" void kernel_launch(void* const* d_in, const int* in_sizes, int n_in,
                              void* d_out, int out_size, void* d_ws, size_t ws_size,
                              hipStream_t stream)
{
    Params pp;
    pp.emb         = (const float*)d_in[0];
    pp.noise_init  = (const float*)d_in[1];
    pp.noise_final = (const float*)d_in[2];
    pp.slots_mu    = (const float*)d_in[3];
    pp.slots_logsg = (const float*)d_in[4];
    pp.mixing_co   = (const float*)d_in[5];
    pp.Wk          = (const float*)d_in[6];
    pp.bk          = (const float*)d_in[7];
    pp.Wq          = (const float*)d_in[8];
    pp.bq          = (const float*)d_in[9];
    pp.Wv          = (const float*)d_in[10];
    pp.bv          = (const float*)d_in[11];
    pp.ln_g        = (const float*)d_in[12];
    pp.ln_b        = (const float*)d_in[13];
    pp.out         = (float*)d_out;

    float* ws = (float*)d_ws;
    pp.queries = ws;
    pp.attn    = pp.queries + BB * KK * DD;
    pp.s1p     = pp.attn + BB * NN * KK;
    pp.s2p     = pp.s1p + (size_t)BB * 32 * KK * DD;
    pp.off     = pp.s2p + (size_t)BB * 32 * KK * DD;
    pp.mix16   = pp.off + BB * 16;
    pp.colsum  = pp.mix16 + BB * 16;
    pp.Abf     = (short*)(pp.colsum + BB * KK);
    pp.Kbf     = pp.Abf + (size_t)BB * NN * DD;
    pp.Vbf     = pp.Kbf + (size_t)BB * NN * DD;
    pp.WtKV    = pp.Vbf + (size_t)BB * NN * DD;
    pp.WqT     = pp.WtKV + (size_t)1024 * DD;
    pp.slotbf  = pp.WqT + (size_t)DD * DD;
    pp.F_bt    = pp.slotbf + (size_t)BB * KK * DD;

    k_pre<<<4992, 256, 0, stream>>>(pp);
    k_gemm<<<1032, 256, 0, stream>>>(pp);
    k_fprep0<<<256, 256, 0, stream>>>(pp);
    for (int it = 0; it < 3; it++) {
        k_gllmu<<<512, 512, 0, stream>>>(pp);
        if (it < 2) k_fprep<<<128, 256, 0, stream>>>(pp);
    }
    k_final<<<768, 256, 0, stream>>>(pp);
}